// Round 1
// baseline (386.723 us; speedup 1.0000x reference)
//
#include <hip/hip_runtime.h>

// Problem constants (fixed by setup_inputs)
#define BATCH 2
#define NPTS  2048      // N (source points, x1/p1)
#define MPTS  8192      // M (query points, x2/p2)
#define CIN1  512       // Cin for up_mlp
#define CIN2  256       // Cin for lateral_mlp
#define COUT  256
#define ROWS1 (BATCH*NPTS)   // 4096
#define ROWS2 (BATCH*MPTS)   // 16384
#define BN_EPS 1e-5f
#define NN_EPS 1e-8f

// ---------------------------------------------------------------------------
// GEMM (NT): C[row][o] = sum_k A[row][k] * W[o][k];  C stride = COUT(=256)
// 64x64 tile, BK=32, 256 threads, 4x4 micro-tile per thread.
// LDS layout [k][m] (transposed on stage) with +4 pad -> aligned b128 reads.
// ---------------------------------------------------------------------------
template<int K>
__global__ __launch_bounds__(256)
void gemm_nt(const float* __restrict__ A, const float* __restrict__ W,
             float* __restrict__ C) {
    constexpr int TILE = 64, BK = 32, LDW = 68;   // 68*4B stride: 16B aligned rows
    __shared__ float As[BK][LDW];
    __shared__ float Bs[BK][LDW];
    const int tid = threadIdx.x;
    const int m0 = blockIdx.y * TILE;
    const int o0 = blockIdx.x * TILE;
    const int tx = tid & 15, ty = tid >> 4;
    const int sr = tid >> 3;          // 0..31  (tile row for staging)
    const int sc = (tid & 7) * 4;     // 0..28  (k offset for staging, float4)
    const float* Ap = A + (size_t)(m0 + sr) * K + sc;
    const float* Wp = W + (size_t)(o0 + sr) * K + sc;
    float acc[4][4] = {};
    for (int k0 = 0; k0 < K; k0 += BK) {
        float4 a0 = *(const float4*)(Ap + k0);
        float4 a1 = *(const float4*)(Ap + k0 + (size_t)32 * K);
        float4 b0 = *(const float4*)(Wp + k0);
        float4 b1 = *(const float4*)(Wp + k0 + (size_t)32 * K);
        __syncthreads();   // protect previous iteration's reads
        As[sc+0][sr]    = a0.x; As[sc+1][sr]    = a0.y; As[sc+2][sr]    = a0.z; As[sc+3][sr]    = a0.w;
        As[sc+0][sr+32] = a1.x; As[sc+1][sr+32] = a1.y; As[sc+2][sr+32] = a1.z; As[sc+3][sr+32] = a1.w;
        Bs[sc+0][sr]    = b0.x; Bs[sc+1][sr]    = b0.y; Bs[sc+2][sr]    = b0.z; Bs[sc+3][sr]    = b0.w;
        Bs[sc+0][sr+32] = b1.x; Bs[sc+1][sr+32] = b1.y; Bs[sc+2][sr+32] = b1.z; Bs[sc+3][sr+32] = b1.w;
        __syncthreads();
        #pragma unroll
        for (int k = 0; k < BK; ++k) {
            float4 av = *(const float4*)&As[k][ty * 4];
            float4 bv = *(const float4*)&Bs[k][tx * 4];
            float a[4] = {av.x, av.y, av.z, av.w};
            float b[4] = {bv.x, bv.y, bv.z, bv.w};
            #pragma unroll
            for (int i = 0; i < 4; ++i)
                #pragma unroll
                for (int j = 0; j < 4; ++j)
                    acc[i][j] = fmaf(a[i], b[j], acc[i][j]);
        }
    }
    #pragma unroll
    for (int i = 0; i < 4; ++i) {
        float4 v = {acc[i][0], acc[i][1], acc[i][2], acc[i][3]};
        *(float4*)&C[(size_t)(m0 + ty * 4 + i) * COUT + o0 + tx * 4] = v;
    }
}

// ---------------------------------------------------------------------------
// Column sums (per-channel sum & sum-of-squares) over a row range; atomics
// into out[0..255]=sum, out[256..511]=sumsq.  blockDim = 256 (1 thread/chan).
// ---------------------------------------------------------------------------
__global__ __launch_bounds__(256)
void colsum256(const float* __restrict__ X, int rowsPerBlock,
               float* __restrict__ out) {
    const int c = threadIdx.x;
    const int r0 = blockIdx.x * rowsPerBlock;
    float s = 0.f, q = 0.f;
    for (int r = 0; r < rowsPerBlock; ++r) {
        float v = X[(size_t)(r0 + r) * COUT + c];
        s += v;
        q = fmaf(v, v, q);
    }
    atomicAdd(&out[c], s);
    atomicAdd(&out[COUT + c], q);
}

// ---------------------------------------------------------------------------
// BN (training-mode, biased var) + ReLU applied in place. grid.x = rows.
// ---------------------------------------------------------------------------
__global__ __launch_bounds__(256)
void bn_relu_inplace(float* __restrict__ X, const float* __restrict__ stats,
                     const float* __restrict__ gamma, const float* __restrict__ beta,
                     float invN) {
    const int c = threadIdx.x;
    const size_t i = (size_t)blockIdx.x * COUT + c;
    const float mean = stats[c] * invN;
    const float var  = fmaf(-mean, mean, stats[COUT + c] * invN);
    const float istd = 1.0f / sqrtf(var + BN_EPS);
    const float v = X[i];
    const float y = (v - mean) * istd * gamma[c] + beta[c];
    X[i] = fmaxf(y, 0.0f);
}

// ---------------------------------------------------------------------------
// three_nn: for each query (b,m) find 3 smallest squared distances to p1[b].
// Same algebraic form as reference: d2 = |q|^2 + |p|^2 - 2*dot.
// Stores idx (int) and normalized weights (float), each (B*M*3).
// ---------------------------------------------------------------------------
__global__ __launch_bounds__(256)
void three_nn_kernel(const float* __restrict__ p1, const float* __restrict__ p2,
                     int* __restrict__ idx, float* __restrict__ wgt) {
    __shared__ float px[NPTS], py[NPTS], pz[NPTS], ps[NPTS];
    const int b = blockIdx.y;
    const float* P1 = p1 + (size_t)b * NPTS * 3;
    for (int i = threadIdx.x; i < NPTS; i += 256) {
        float x = P1[i * 3 + 0], y = P1[i * 3 + 1], z = P1[i * 3 + 2];
        px[i] = x; py[i] = y; pz[i] = z;
        ps[i] = x * x + y * y + z * z;
    }
    __syncthreads();
    const int m = blockIdx.x * 256 + threadIdx.x;
    const float* q = p2 + ((size_t)b * MPTS + m) * 3;
    const float qx = q[0], qy = q[1], qz = q[2];
    const float s2 = qx * qx + qy * qy + qz * qz;
    float d0 = 1e30f, d1 = 1e30f, d2 = 1e30f;
    int   i0 = 0,     i1 = 0,     i2 = 0;
    #pragma unroll 4
    for (int n = 0; n < NPTS; ++n) {
        float dot = px[n] * qx + py[n] * qy + pz[n] * qz;
        float d = s2 + ps[n] - 2.0f * dot;
        if (d < d2) {                       // strict '<' keeps earlier index on ties
            if (d < d1) {
                d2 = d1; i2 = i1;
                if (d < d0) { d1 = d0; i1 = i0; d0 = d; i0 = n; }
                else        { d1 = d;  i1 = n; }
            } else { d2 = d; i2 = n; }
        }
    }
    const float r0 = 1.0f / (d0 + NN_EPS);
    const float r1 = 1.0f / (d1 + NN_EPS);
    const float r2 = 1.0f / (d2 + NN_EPS);
    const float rs = r0 + r1 + r2;
    const size_t o = ((size_t)b * MPTS + m) * 3;
    idx[o + 0] = i0; idx[o + 1] = i1; idx[o + 2] = i2;
    wgt[o + 0] = r0 / rs; wgt[o + 1] = r1 / rs; wgt[o + 2] = r2 / rs;
}

// ---------------------------------------------------------------------------
// Final: out[row][c] = relu(BN2(h2pre)) + sum_k w_k * h1n[b, idx_k, c]
// h2pre lives in d_out already (in-place). grid.x = B*M rows, block = 256.
// stats layout: [0:256)=sum1 [256:512)=sq1 [512:768)=sum2 [768:1024)=sq2
// ---------------------------------------------------------------------------
__global__ __launch_bounds__(256)
void final_combine(const float* __restrict__ h1n, const float* __restrict__ stats,
                   const float* __restrict__ gamma2, const float* __restrict__ beta2,
                   const int* __restrict__ idx, const float* __restrict__ wgt,
                   float* __restrict__ out) {
    const int c = threadIdx.x;
    const int row = blockIdx.x;            // b*M + m
    const int b = row >> 13;               // /8192
    const size_t o3 = (size_t)row * 3;
    const int i0 = idx[o3 + 0], i1 = idx[o3 + 1], i2 = idx[o3 + 2];
    const float w0 = wgt[o3 + 0], w1 = wgt[o3 + 1], w2 = wgt[o3 + 2];
    const float* hb = h1n + (size_t)b * NPTS * COUT;
    float g = w0 * hb[(size_t)i0 * COUT + c]
            + w1 * hb[(size_t)i1 * COUT + c]
            + w2 * hb[(size_t)i2 * COUT + c];
    const float invN = 1.0f / (float)ROWS2;
    const float mean = stats[512 + c] * invN;
    const float var  = fmaf(-mean, mean, stats[768 + c] * invN);
    const float istd = 1.0f / sqrtf(var + BN_EPS);
    const size_t oi = (size_t)row * COUT + c;
    const float v = out[oi];
    const float y = fmaxf((v - mean) * istd * gamma2[c] + beta2[c], 0.0f);
    out[oi] = y + g;
}

// ---------------------------------------------------------------------------
extern "C" void kernel_launch(void* const* d_in, const int* in_sizes, int n_in,
                              void* d_out, int out_size, void* d_ws, size_t ws_size,
                              hipStream_t stream) {
    const float* x1       = (const float*)d_in[0];  // (B,N,Cin1)
    const float* p1       = (const float*)d_in[1];  // (B,N,3)
    const float* x2       = (const float*)d_in[2];  // (B,M,Cin2)
    const float* p2       = (const float*)d_in[3];  // (B,M,3)
    const float* W_up     = (const float*)d_in[4];  // (COUT,CIN1)
    const float* gamma_up = (const float*)d_in[5];
    const float* beta_up  = (const float*)d_in[6];
    const float* W_lat    = (const float*)d_in[7];  // (COUT,CIN2)
    const float* gamma_lat= (const float*)d_in[8];
    const float* beta_lat = (const float*)d_in[9];
    float* out = (float*)d_out;

    // workspace layout
    float* h1    = (float*)d_ws;                    // ROWS1*COUT
    float* stats = h1 + (size_t)ROWS1 * COUT;       // 1024 floats
    int*   idx   = (int*)(stats + 1024);            // ROWS2*3
    float* wgt   = (float*)(idx + (size_t)ROWS2 * 3);

    hipMemsetAsync(stats, 0, 1024 * sizeof(float), stream);

    // up_mlp GEMM: h1pre = x1 * W_up^T   (ROWS1 x COUT)
    gemm_nt<CIN1><<<dim3(COUT / 64, ROWS1 / 64), 256, 0, stream>>>(x1, W_up, h1);
    colsum256<<<ROWS1 / 64, 256, 0, stream>>>(h1, 64, stats);
    bn_relu_inplace<<<ROWS1, 256, 0, stream>>>(h1, stats, gamma_up, beta_up,
                                               1.0f / (float)ROWS1);

    // lateral GEMM straight into d_out's y region (same (b,m,c) layout)
    gemm_nt<CIN2><<<dim3(COUT / 64, ROWS2 / 64), 256, 0, stream>>>(x2, W_lat, out);
    colsum256<<<ROWS2 / 64, 256, 0, stream>>>(out, 64, stats + 512);

    // 3-NN + weights
    three_nn_kernel<<<dim3(MPTS / 256, BATCH), 256, 0, stream>>>(p1, p2, idx, wgt);

    // gather-interp + BN2 + ReLU + add (in place on d_out)
    final_combine<<<ROWS2, 256, 0, stream>>>(h1, stats, gamma_lat, beta_lat,
                                             idx, wgt, out);

    // p2 passthrough -> second output
    hipMemcpyAsync(out + (size_t)ROWS2 * COUT, p2,
                   (size_t)ROWS2 * 3 * sizeof(float),
                   hipMemcpyDeviceToDevice, stream);
}

// Round 2
// 239.319 us; speedup vs baseline: 1.6159x; 1.6159x over previous
//
#include <hip/hip_runtime.h>

// Problem constants (fixed by setup_inputs)
#define BATCH 2
#define NPTS  2048      // N (source points, x1/p1)
#define MPTS  8192      // M (query points, x2/p2)
#define CIN1  512       // Cin for up_mlp
#define CIN2  256       // Cin for lateral_mlp
#define COUT  256
#define ROWS1 (BATCH*NPTS)   // 4096
#define ROWS2 (BATCH*MPTS)   // 16384
#define BN_EPS 1e-5f
#define NN_EPS 1e-8f

// three_nn split-N decomposition
#define NCHUNK 8
#define CHUNK  (NPTS / NCHUNK)   // 256 points per chunk

// ---------------------------------------------------------------------------
// GEMM (NT): C[row][o] = sum_k A[row][k] * W[o][k];  C stride = COUT(=256)
// 64x64 tile, BK=32, 256 threads, 4x4 micro-tile per thread.
// ---------------------------------------------------------------------------
template<int K>
__global__ __launch_bounds__(256)
void gemm_nt(const float* __restrict__ A, const float* __restrict__ W,
             float* __restrict__ C) {
    constexpr int TILE = 64, BK = 32, LDW = 68;
    __shared__ float As[BK][LDW];
    __shared__ float Bs[BK][LDW];
    const int tid = threadIdx.x;
    const int m0 = blockIdx.y * TILE;
    const int o0 = blockIdx.x * TILE;
    const int tx = tid & 15, ty = tid >> 4;
    const int sr = tid >> 3;          // 0..31
    const int sc = (tid & 7) * 4;     // 0..28
    const float* Ap = A + (size_t)(m0 + sr) * K + sc;
    const float* Wp = W + (size_t)(o0 + sr) * K + sc;
    float acc[4][4] = {};
    for (int k0 = 0; k0 < K; k0 += BK) {
        float4 a0 = *(const float4*)(Ap + k0);
        float4 a1 = *(const float4*)(Ap + k0 + (size_t)32 * K);
        float4 b0 = *(const float4*)(Wp + k0);
        float4 b1 = *(const float4*)(Wp + k0 + (size_t)32 * K);
        __syncthreads();
        As[sc+0][sr]    = a0.x; As[sc+1][sr]    = a0.y; As[sc+2][sr]    = a0.z; As[sc+3][sr]    = a0.w;
        As[sc+0][sr+32] = a1.x; As[sc+1][sr+32] = a1.y; As[sc+2][sr+32] = a1.z; As[sc+3][sr+32] = a1.w;
        Bs[sc+0][sr]    = b0.x; Bs[sc+1][sr]    = b0.y; Bs[sc+2][sr]    = b0.z; Bs[sc+3][sr]    = b0.w;
        Bs[sc+0][sr+32] = b1.x; Bs[sc+1][sr+32] = b1.y; Bs[sc+2][sr+32] = b1.z; Bs[sc+3][sr+32] = b1.w;
        __syncthreads();
        #pragma unroll
        for (int k = 0; k < BK; ++k) {
            float4 av = *(const float4*)&As[k][ty * 4];
            float4 bv = *(const float4*)&Bs[k][tx * 4];
            float a[4] = {av.x, av.y, av.z, av.w};
            float b[4] = {bv.x, bv.y, bv.z, bv.w};
            #pragma unroll
            for (int i = 0; i < 4; ++i)
                #pragma unroll
                for (int j = 0; j < 4; ++j)
                    acc[i][j] = fmaf(a[i], b[j], acc[i][j]);
        }
    }
    #pragma unroll
    for (int i = 0; i < 4; ++i) {
        float4 v = {acc[i][0], acc[i][1], acc[i][2], acc[i][3]};
        *(float4*)&C[(size_t)(m0 + ty * 4 + i) * COUT + o0 + tx * 4] = v;
    }
}

// ---------------------------------------------------------------------------
// Column sums (per-channel sum & sum-of-squares); atomics into
// out[0..255]=sum, out[256..511]=sumsq.  blockDim = 256.
// ---------------------------------------------------------------------------
__global__ __launch_bounds__(256)
void colsum256(const float* __restrict__ X, int rowsPerBlock,
               float* __restrict__ out) {
    const int c = threadIdx.x;
    const int r0 = blockIdx.x * rowsPerBlock;
    float s = 0.f, q = 0.f;
    for (int r = 0; r < rowsPerBlock; ++r) {
        float v = X[(size_t)(r0 + r) * COUT + c];
        s += v;
        q = fmaf(v, v, q);
    }
    atomicAdd(&out[c], s);
    atomicAdd(&out[COUT + c], q);
}

// ---------------------------------------------------------------------------
// BN (training-mode, biased var) + ReLU applied in place. grid.x = rows.
// ---------------------------------------------------------------------------
__global__ __launch_bounds__(256)
void bn_relu_inplace(float* __restrict__ X, const float* __restrict__ stats,
                     const float* __restrict__ gamma, const float* __restrict__ beta,
                     float invN) {
    const int c = threadIdx.x;
    const size_t i = (size_t)blockIdx.x * COUT + c;
    const float mean = stats[c] * invN;
    const float var  = fmaf(-mean, mean, stats[COUT + c] * invN);
    const float istd = 1.0f / sqrtf(var + BN_EPS);
    const float v = X[i];
    const float y = (v - mean) * istd * gamma[c] + beta[c];
    X[i] = fmaxf(y, 0.0f);
}

// ---------------------------------------------------------------------------
// three_nn phase 1: each block = 256 queries x one 256-point chunk.
// Stages chunk as float4 (x,y,z,|p|^2) in LDS; broadcast reads (no conflict).
// Writes per-(query,chunk) top-3 (d, idx) pairs.
// part layout: [(b*MPTS+m) * NCHUNK + c] * 3  float2 entries.
// ---------------------------------------------------------------------------
__global__ __launch_bounds__(256)
void three_nn_part(const float* __restrict__ p1, const float* __restrict__ p2,
                   float2* __restrict__ part) {
    __shared__ float4 pts[CHUNK];
    const int b = blockIdx.z;
    const int c = blockIdx.y;
    const int t = threadIdx.x;
    const int n0 = c * CHUNK;
    const float* P1 = p1 + ((size_t)b * NPTS + n0) * 3;
    {
        float x = P1[t * 3 + 0], y = P1[t * 3 + 1], z = P1[t * 3 + 2];
        pts[t] = make_float4(x, y, z, x * x + y * y + z * z);
    }
    __syncthreads();
    const int m = blockIdx.x * 256 + t;
    const float* q = p2 + ((size_t)b * MPTS + m) * 3;
    const float qx = q[0], qy = q[1], qz = q[2];
    const float s2 = qx * qx + qy * qy + qz * qz;
    float d0 = 1e30f, d1 = 1e30f, d2 = 1e30f;
    int   i0 = 0,     i1 = 0,     i2 = 0;
    #pragma unroll 4
    for (int n = 0; n < CHUNK; ++n) {
        float4 p = pts[n];
        float dot = p.x * qx + p.y * qy + p.z * qz;
        float d = s2 + p.w - 2.0f * dot;   // same algebraic form as reference
        if (d < d2) {                      // strict '<': earliest index wins ties
            if (d < d1) {
                d2 = d1; i2 = i1;
                if (d < d0) { d1 = d0; i1 = i0; d0 = d; i0 = n0 + n; }
                else        { d1 = d;  i1 = n0 + n; }
            } else { d2 = d; i2 = n0 + n; }
        }
    }
    float2* o = part + ((size_t)(b * MPTS + m) * NCHUNK + c) * 3;
    o[0] = make_float2(d0, __int_as_float(i0));
    o[1] = make_float2(d1, __int_as_float(i1));
    o[2] = make_float2(d2, __int_as_float(i2));
}

// ---------------------------------------------------------------------------
// three_nn phase 2: merge NCHUNK partial top-3 lists per query (in chunk
// order = ascending index order, so strict '<' keeps reference tie-order),
// then compute normalized inverse-distance weights.
// ---------------------------------------------------------------------------
__global__ __launch_bounds__(256)
void three_nn_merge(const float2* __restrict__ part,
                    int* __restrict__ idx, float* __restrict__ wgt) {
    const int row = blockIdx.x * 256 + threadIdx.x;   // b*MPTS + m
    const float4* pp = (const float4*)(part + (size_t)row * NCHUNK * 3);
    float d0 = 1e30f, d1 = 1e30f, d2 = 1e30f;
    int   i0 = 0,     i1 = 0,     i2 = 0;
    #pragma unroll
    for (int j = 0; j < NCHUNK * 3 / 2; ++j) {        // 12 float4 = 24 pairs
        float4 v = pp[j];
        #pragma unroll
        for (int h = 0; h < 2; ++h) {
            float d = h ? v.z : v.x;
            int   i = __float_as_int(h ? v.w : v.y);
            if (d < d2) {
                if (d < d1) {
                    d2 = d1; i2 = i1;
                    if (d < d0) { d1 = d0; i1 = i0; d0 = d; i0 = i; }
                    else        { d1 = d;  i1 = i; }
                } else { d2 = d; i2 = i; }
            }
        }
    }
    const float r0 = 1.0f / (d0 + NN_EPS);
    const float r1 = 1.0f / (d1 + NN_EPS);
    const float r2 = 1.0f / (d2 + NN_EPS);
    const float rs = r0 + r1 + r2;
    const size_t o = (size_t)row * 3;
    idx[o + 0] = i0; idx[o + 1] = i1; idx[o + 2] = i2;
    wgt[o + 0] = r0 / rs; wgt[o + 1] = r1 / rs; wgt[o + 2] = r2 / rs;
}

// ---------------------------------------------------------------------------
// Final: out[row][c] = relu(BN2(h2pre)) + sum_k w_k * h1n[b, idx_k, c]
// ---------------------------------------------------------------------------
__global__ __launch_bounds__(256)
void final_combine(const float* __restrict__ h1n, const float* __restrict__ stats,
                   const float* __restrict__ gamma2, const float* __restrict__ beta2,
                   const int* __restrict__ idx, const float* __restrict__ wgt,
                   float* __restrict__ out) {
    const int c = threadIdx.x;
    const int row = blockIdx.x;            // b*M + m
    const int b = row >> 13;               // /8192
    const size_t o3 = (size_t)row * 3;
    const int i0 = idx[o3 + 0], i1 = idx[o3 + 1], i2 = idx[o3 + 2];
    const float w0 = wgt[o3 + 0], w1 = wgt[o3 + 1], w2 = wgt[o3 + 2];
    const float* hb = h1n + (size_t)b * NPTS * COUT;
    float g = w0 * hb[(size_t)i0 * COUT + c]
            + w1 * hb[(size_t)i1 * COUT + c]
            + w2 * hb[(size_t)i2 * COUT + c];
    const float invN = 1.0f / (float)ROWS2;
    const float mean = stats[512 + c] * invN;
    const float var  = fmaf(-mean, mean, stats[768 + c] * invN);
    const float istd = 1.0f / sqrtf(var + BN_EPS);
    const size_t oi = (size_t)row * COUT + c;
    const float v = out[oi];
    const float y = fmaxf((v - mean) * istd * gamma2[c] + beta2[c], 0.0f);
    out[oi] = y + g;
}

// ---------------------------------------------------------------------------
extern "C" void kernel_launch(void* const* d_in, const int* in_sizes, int n_in,
                              void* d_out, int out_size, void* d_ws, size_t ws_size,
                              hipStream_t stream) {
    const float* x1       = (const float*)d_in[0];  // (B,N,Cin1)
    const float* p1       = (const float*)d_in[1];  // (B,N,3)
    const float* x2       = (const float*)d_in[2];  // (B,M,Cin2)
    const float* p2       = (const float*)d_in[3];  // (B,M,3)
    const float* W_up     = (const float*)d_in[4];  // (COUT,CIN1)
    const float* gamma_up = (const float*)d_in[5];
    const float* beta_up  = (const float*)d_in[6];
    const float* W_lat    = (const float*)d_in[7];  // (COUT,CIN2)
    const float* gamma_lat= (const float*)d_in[8];
    const float* beta_lat = (const float*)d_in[9];
    float* out = (float*)d_out;

    // workspace layout (~7.8 MB)
    float*  h1    = (float*)d_ws;                        // ROWS1*COUT
    float*  stats = h1 + (size_t)ROWS1 * COUT;           // 1024 floats
    int*    idx   = (int*)(stats + 1024);                // ROWS2*3
    float*  wgt   = (float*)(idx + (size_t)ROWS2 * 3);   // ROWS2*3
    float2* part  = (float2*)(wgt + (size_t)ROWS2 * 3);  // ROWS2*NCHUNK*3 float2

    hipMemsetAsync(stats, 0, 1024 * sizeof(float), stream);

    // up_mlp GEMM: h1pre = x1 * W_up^T   (ROWS1 x COUT)
    gemm_nt<CIN1><<<dim3(COUT / 64, ROWS1 / 64), 256, 0, stream>>>(x1, W_up, h1);
    colsum256<<<ROWS1 / 64, 256, 0, stream>>>(h1, 64, stats);
    bn_relu_inplace<<<ROWS1, 256, 0, stream>>>(h1, stats, gamma_up, beta_up,
                                               1.0f / (float)ROWS1);

    // lateral GEMM straight into d_out's y region (same (b,m,c) layout)
    gemm_nt<CIN2><<<dim3(COUT / 64, ROWS2 / 64), 256, 0, stream>>>(x2, W_lat, out);
    colsum256<<<ROWS2 / 64, 256, 0, stream>>>(out, 64, stats + 512);

    // 3-NN: split-N partials then merge
    three_nn_part<<<dim3(MPTS / 256, NCHUNK, BATCH), 256, 0, stream>>>(p1, p2, part);
    three_nn_merge<<<ROWS2 / 256, 256, 0, stream>>>(part, idx, wgt);

    // gather-interp + BN2 + ReLU + add (in place on d_out)
    final_combine<<<ROWS2, 256, 0, stream>>>(h1, stats, gamma_lat, beta_lat,
                                             idx, wgt, out);

    // p2 passthrough -> second output
    hipMemcpyAsync(out + (size_t)ROWS2 * COUT, p2,
                   (size_t)ROWS2 * 3 * sizeof(float),
                   hipMemcpyDeviceToDevice, stream);
}

// Round 3
// 198.054 us; speedup vs baseline: 1.9526x; 1.2084x over previous
//
#include <hip/hip_runtime.h>

// Problem constants (fixed by setup_inputs)
#define BATCH 2
#define NPTS  2048      // N (source points, x1/p1)
#define MPTS  8192      // M (query points, x2/p2)
#define CIN1  512       // Cin for up_mlp
#define CIN2  256       // Cin for lateral_mlp
#define COUT  256
#define ROWS1 (BATCH*NPTS)   // 4096
#define ROWS2 (BATCH*MPTS)   // 16384
#define BN_EPS 1e-5f
#define NN_EPS 1e-8f

// three_nn split-N decomposition
#define NCHUNK 16
#define CHUNK  (NPTS / NCHUNK)   // 128 points per chunk

typedef __attribute__((ext_vector_type(8))) short  bf16x8;  // 8 bf16 = 4 VGPRs
typedef __attribute__((ext_vector_type(4))) float  f32x4;   // MFMA acc

__device__ __forceinline__ unsigned short bf16_rne(float x) {
    unsigned u = __float_as_uint(x);
    u += 0x7FFFu + ((u >> 16) & 1u);
    return (unsigned short)(u >> 16);
}
__device__ __forceinline__ float bf16_f32(unsigned short h) {
    return __uint_as_float(((unsigned)h) << 16);
}
__device__ __forceinline__ void split2(float x, unsigned short& h, unsigned short& l) {
    h = bf16_rne(x);
    l = bf16_rne(x - bf16_f32(h));
}

// ---------------------------------------------------------------------------
// Split-bf16 MFMA GEMM (NT): C[row][o] = sum_k A[row][k]*W[o][k], C ld = COUT.
// f32 = hi + lo (bf16 each); C = Ah*Bh + Al*Bh + Ah*Bl (3 MFMA passes).
// 256 threads = 4 waves in 2x2; wave tile (BM/2)x(BN/2); 16x16x32 bf16 MFMA.
// Epilogue: per-channel sum & sumsq of C tile -> atomicAdd into stats[0:COUT)
// and stats[COUT:2*COUT)  (BN training stats, fused).
// ---------------------------------------------------------------------------
template<int K, int BM, int BN>
__global__ __launch_bounds__(256)
void gemm_mfma(const float* __restrict__ A, const float* __restrict__ W,
               float* __restrict__ C, float* __restrict__ stats) {
    constexpr int BK = 32;          // f32 k per stage
    constexpr int LDK = 40;         // padded row length (bf16) -> conflict-free
    constexpr int WM = BM / 2, WN = BN / 2;
    constexpr int FM = WM / 16, FN = WN / 16;
    __shared__ unsigned short Ah[BM][LDK], Al[BM][LDK];
    __shared__ unsigned short Bh[BN][LDK], Bl[BN][LDK];
    __shared__ float red[BN][8];

    const int tid = threadIdx.x;
    const int m0 = blockIdx.y * BM;
    const int o0 = blockIdx.x * BN;
    const int lane = tid & 63, wid = tid >> 6;
    const int wy = wid >> 1, wx = wid & 1;
    const int lr = lane & 15, lg = lane >> 4;
    const int srow = tid >> 3;            // 0..31 staging row
    const int squad = (tid & 7) * 4;      // staging k offset (float4)

    f32x4 acc[FM][FN];
    #pragma unroll
    for (int i = 0; i < FM; ++i)
        #pragma unroll
        for (int j = 0; j < FN; ++j)
            acc[i][j] = (f32x4){0.f, 0.f, 0.f, 0.f};

    const float* Abase = A + (size_t)m0 * K + squad;
    const float* Wbase = W + (size_t)o0 * K + squad;

    for (int k0 = 0; k0 < K; k0 += BK) {
        __syncthreads();   // previous iteration's frag reads done
        #pragma unroll
        for (int r = srow; r < BM; r += 32) {
            float4 v = *(const float4*)(Abase + (size_t)r * K + k0);
            ushort4 h, l;
            split2(v.x, h.x, l.x); split2(v.y, h.y, l.y);
            split2(v.z, h.z, l.z); split2(v.w, h.w, l.w);
            *(ushort4*)&Ah[r][squad] = h;
            *(ushort4*)&Al[r][squad] = l;
        }
        #pragma unroll
        for (int r = srow; r < BN; r += 32) {
            float4 v = *(const float4*)(Wbase + (size_t)r * K + k0);
            ushort4 h, l;
            split2(v.x, h.x, l.x); split2(v.y, h.y, l.y);
            split2(v.z, h.z, l.z); split2(v.w, h.w, l.w);
            *(ushort4*)&Bh[r][squad] = h;
            *(ushort4*)&Bl[r][squad] = l;
        }
        __syncthreads();

        bf16x8 fah[FM], fal[FM], fbh[FN], fbl[FN];
        #pragma unroll
        for (int i = 0; i < FM; ++i) {
            const int row = wy * WM + i * 16 + lr;
            fah[i] = *(const bf16x8*)&Ah[row][lg * 8];
            fal[i] = *(const bf16x8*)&Al[row][lg * 8];
        }
        #pragma unroll
        for (int j = 0; j < FN; ++j) {
            const int row = wx * WN + j * 16 + lr;
            fbh[j] = *(const bf16x8*)&Bh[row][lg * 8];
            fbl[j] = *(const bf16x8*)&Bl[row][lg * 8];
        }
        #pragma unroll
        for (int i = 0; i < FM; ++i)
            #pragma unroll
            for (int j = 0; j < FN; ++j) {
                acc[i][j] = __builtin_amdgcn_mfma_f32_16x16x32_bf16(fah[i], fbh[j], acc[i][j], 0, 0, 0);
                acc[i][j] = __builtin_amdgcn_mfma_f32_16x16x32_bf16(fal[i], fbh[j], acc[i][j], 0, 0, 0);
                acc[i][j] = __builtin_amdgcn_mfma_f32_16x16x32_bf16(fah[i], fbl[j], acc[i][j], 0, 0, 0);
            }
    }

    // C store: D lane mapping col = lane&15, row = (lane>>4)*4 + reg
    #pragma unroll
    for (int i = 0; i < FM; ++i)
        #pragma unroll
        for (int j = 0; j < FN; ++j) {
            const int col = o0 + wx * WN + j * 16 + lr;
            const int rbase = m0 + wy * WM + i * 16 + lg * 4;
            #pragma unroll
            for (int r = 0; r < 4; ++r)
                C[(size_t)(rbase + r) * COUT + col] = acc[i][j][r];
        }

    // fused per-channel stats: sum over this tile's BM rows per column
    #pragma unroll
    for (int j = 0; j < FN; ++j) {
        float s = 0.f;
        #pragma unroll
        for (int i = 0; i < FM; ++i)
            #pragma unroll
            for (int r = 0; r < 4; ++r)
                s += acc[i][j][r];
        red[wx * WN + j * 16 + lr][wy * 4 + lg] = s;
    }
    __syncthreads();
    if (tid < BN) {
        float s = 0.f;
        #pragma unroll
        for (int k = 0; k < 8; ++k) s += red[tid][k];
        atomicAdd(&stats[o0 + tid], s);
    }
    __syncthreads();
    #pragma unroll
    for (int j = 0; j < FN; ++j) {
        float q = 0.f;
        #pragma unroll
        for (int i = 0; i < FM; ++i)
            #pragma unroll
            for (int r = 0; r < 4; ++r)
                q = fmaf(acc[i][j][r], acc[i][j][r], q);
        red[wx * WN + j * 16 + lr][wy * 4 + lg] = q;
    }
    __syncthreads();
    if (tid < BN) {
        float q = 0.f;
        #pragma unroll
        for (int k = 0; k < 8; ++k) q += red[tid][k];
        atomicAdd(&stats[COUT + o0 + tid], q);
    }
}

// ---------------------------------------------------------------------------
// three_nn phase 1: each block = 256 queries x one 128-point chunk.
// ---------------------------------------------------------------------------
__global__ __launch_bounds__(256)
void three_nn_part(const float* __restrict__ p1, const float* __restrict__ p2,
                   float2* __restrict__ part) {
    __shared__ float4 pts[CHUNK];
    const int b = blockIdx.z;
    const int c = blockIdx.y;
    const int t = threadIdx.x;
    const int n0 = c * CHUNK;
    if (t < CHUNK) {
        const float* P1 = p1 + ((size_t)b * NPTS + n0) * 3;
        float x = P1[t * 3 + 0], y = P1[t * 3 + 1], z = P1[t * 3 + 2];
        pts[t] = make_float4(x, y, z, x * x + y * y + z * z);
    }
    __syncthreads();
    const int m = blockIdx.x * 256 + t;
    const float* q = p2 + ((size_t)b * MPTS + m) * 3;
    const float qx = q[0], qy = q[1], qz = q[2];
    const float s2 = qx * qx + qy * qy + qz * qz;
    float d0 = 1e30f, d1 = 1e30f, d2 = 1e30f;
    int   i0 = 0,     i1 = 0,     i2 = 0;
    #pragma unroll 4
    for (int n = 0; n < CHUNK; ++n) {
        float4 p = pts[n];
        float dot = p.x * qx + p.y * qy + p.z * qz;
        float d = s2 + p.w - 2.0f * dot;   // same algebraic form as reference
        if (d < d2) {                      // strict '<': earliest index wins ties
            if (d < d1) {
                d2 = d1; i2 = i1;
                if (d < d0) { d1 = d0; i1 = i0; d0 = d; i0 = n0 + n; }
                else        { d1 = d;  i1 = n0 + n; }
            } else { d2 = d; i2 = n0 + n; }
        }
    }
    float2* o = part + ((size_t)(b * MPTS + m) * NCHUNK + c) * 3;
    o[0] = make_float2(d0, __int_as_float(i0));
    o[1] = make_float2(d1, __int_as_float(i1));
    o[2] = make_float2(d2, __int_as_float(i2));
}

// ---------------------------------------------------------------------------
// three_nn phase 2: merge NCHUNK partial top-3 lists (chunk order = ascending
// index order -> strict '<' keeps reference tie-order), compute weights.
// ---------------------------------------------------------------------------
__global__ __launch_bounds__(256)
void three_nn_merge(const float2* __restrict__ part,
                    int* __restrict__ idx, float* __restrict__ wgt) {
    const int row = blockIdx.x * 256 + threadIdx.x;   // b*MPTS + m
    const float4* pp = (const float4*)(part + (size_t)row * NCHUNK * 3);
    float d0 = 1e30f, d1 = 1e30f, d2 = 1e30f;
    int   i0 = 0,     i1 = 0,     i2 = 0;
    #pragma unroll
    for (int j = 0; j < NCHUNK * 3 / 2; ++j) {        // 24 float4 = 48 pairs
        float4 v = pp[j];
        #pragma unroll
        for (int h = 0; h < 2; ++h) {
            float d = h ? v.z : v.x;
            int   i = __float_as_int(h ? v.w : v.y);
            if (d < d2) {
                if (d < d1) {
                    d2 = d1; i2 = i1;
                    if (d < d0) { d1 = d0; i1 = i0; d0 = d; i0 = i; }
                    else        { d1 = d;  i1 = i; }
                } else { d2 = d; i2 = i; }
            }
        }
    }
    const float r0 = 1.0f / (d0 + NN_EPS);
    const float r1 = 1.0f / (d1 + NN_EPS);
    const float r2 = 1.0f / (d2 + NN_EPS);
    const float rs = r0 + r1 + r2;
    const size_t o = (size_t)row * 3;
    idx[o + 0] = i0; idx[o + 1] = i1; idx[o + 2] = i2;
    wgt[o + 0] = r0 / rs; wgt[o + 1] = r1 / rs; wgt[o + 2] = r2 / rs;
}

// ---------------------------------------------------------------------------
// Final: out[row][c] = relu(BN2(h2pre)) + sum_k w_k * relu(BN1(h1pre[idx_k][c]))
// h2pre lives in d_out (in-place). BN1 folded into the gather.
// stats layout: [0:256)=sum1 [256:512)=sq1 [512:768)=sum2 [768:1024)=sq2
// ---------------------------------------------------------------------------
__global__ __launch_bounds__(256)
void final_combine(const float* __restrict__ h1, const float* __restrict__ stats,
                   const float* __restrict__ g1, const float* __restrict__ b1,
                   const float* __restrict__ g2, const float* __restrict__ b2,
                   const int* __restrict__ idx, const float* __restrict__ wgt,
                   float* __restrict__ out) {
    const int c = threadIdx.x;
    const int row = blockIdx.x;            // b*M + m
    const int b = row >> 13;               // /8192
    // BN1 affine for channel c
    const float inv1 = 1.0f / (float)ROWS1;
    const float mean1 = stats[c] * inv1;
    const float var1  = fmaf(-mean1, mean1, stats[COUT + c] * inv1);
    const float sc1   = g1[c] / sqrtf(var1 + BN_EPS);
    const float sh1   = fmaf(-mean1, sc1, b1[c]);
    // BN2 affine for channel c
    const float inv2 = 1.0f / (float)ROWS2;
    const float mean2 = stats[512 + c] * inv2;
    const float var2  = fmaf(-mean2, mean2, stats[768 + c] * inv2);
    const float sc2   = g2[c] / sqrtf(var2 + BN_EPS);
    const float sh2   = fmaf(-mean2, sc2, b2[c]);

    const size_t o3 = (size_t)row * 3;
    const int i0 = idx[o3 + 0], i1 = idx[o3 + 1], i2 = idx[o3 + 2];
    const float w0 = wgt[o3 + 0], w1 = wgt[o3 + 1], w2 = wgt[o3 + 2];
    const float* hb = h1 + (size_t)b * NPTS * COUT;
    const float v0 = fmaxf(fmaf(hb[(size_t)i0 * COUT + c], sc1, sh1), 0.f);
    const float v1 = fmaxf(fmaf(hb[(size_t)i1 * COUT + c], sc1, sh1), 0.f);
    const float v2 = fmaxf(fmaf(hb[(size_t)i2 * COUT + c], sc1, sh1), 0.f);
    const float g = w0 * v0 + w1 * v1 + w2 * v2;

    const size_t oi = (size_t)row * COUT + c;
    const float y = fmaxf(fmaf(out[oi], sc2, sh2), 0.f);
    out[oi] = y + g;
}

// ---------------------------------------------------------------------------
extern "C" void kernel_launch(void* const* d_in, const int* in_sizes, int n_in,
                              void* d_out, int out_size, void* d_ws, size_t ws_size,
                              hipStream_t stream) {
    const float* x1       = (const float*)d_in[0];  // (B,N,Cin1)
    const float* p1       = (const float*)d_in[1];  // (B,N,3)
    const float* x2       = (const float*)d_in[2];  // (B,M,Cin2)
    const float* p2       = (const float*)d_in[3];  // (B,M,3)
    const float* W_up     = (const float*)d_in[4];  // (COUT,CIN1)
    const float* gamma_up = (const float*)d_in[5];
    const float* beta_up  = (const float*)d_in[6];
    const float* W_lat    = (const float*)d_in[7];  // (COUT,CIN2)
    const float* gamma_lat= (const float*)d_in[8];
    const float* beta_lat = (const float*)d_in[9];
    float* out = (float*)d_out;

    // workspace layout (~11 MB)
    float*  h1    = (float*)d_ws;                        // ROWS1*COUT (pre-BN)
    float*  stats = h1 + (size_t)ROWS1 * COUT;           // 1024 floats
    int*    idx   = (int*)(stats + 1024);                // ROWS2*3
    float*  wgt   = (float*)(idx + (size_t)ROWS2 * 3);   // ROWS2*3
    float2* part  = (float2*)(wgt + (size_t)ROWS2 * 3);  // ROWS2*NCHUNK*3 float2

    hipMemsetAsync(stats, 0, 1024 * sizeof(float), stream);

    // up_mlp GEMM (split-bf16 MFMA) + fused BN1 stats
    gemm_mfma<CIN1, 64, 64><<<dim3(COUT / 64, ROWS1 / 64), 256, 0, stream>>>(
        x1, W_up, h1, stats);

    // lateral GEMM straight into d_out's y region + fused BN2 stats
    gemm_mfma<CIN2, 128, 128><<<dim3(COUT / 128, ROWS2 / 128), 256, 0, stream>>>(
        x2, W_lat, out, stats + 512);

    // 3-NN: split-N partials then merge
    three_nn_part<<<dim3(MPTS / 256, NCHUNK, BATCH), 256, 0, stream>>>(p1, p2, part);
    three_nn_merge<<<ROWS2 / 256, 256, 0, stream>>>(part, idx, wgt);

    // gather-interp (+BN1+ReLU) + BN2 + ReLU + add, in place on d_out
    final_combine<<<ROWS2, 256, 0, stream>>>(h1, stats, gamma_up, beta_up,
                                             gamma_lat, beta_lat, idx, wgt, out);

    // p2 passthrough -> second output
    hipMemcpyAsync(out + (size_t)ROWS2 * COUT, p2,
                   (size_t)ROWS2 * 3 * sizeof(float),
                   hipMemcpyDeviceToDevice, stream);
}

// Round 4
// 179.739 us; speedup vs baseline: 2.1516x; 1.1019x over previous
//
#include <hip/hip_runtime.h>

// Problem constants (fixed by setup_inputs)
#define BATCH 2
#define NPTS  2048      // N (source points, x1/p1)
#define MPTS  8192      // M (query points, x2/p2)
#define CIN1  512       // Cin for up_mlp
#define CIN2  256       // Cin for lateral_mlp
#define COUT  256
#define ROWS1 (BATCH*NPTS)   // 4096
#define ROWS2 (BATCH*MPTS)   // 16384
#define BN_EPS 1e-5f
#define NN_EPS 1e-8f

// three_nn split-N decomposition
#define NCHUNK 16
#define CHUNK  (NPTS / NCHUNK)   // 128 points per chunk

typedef __attribute__((ext_vector_type(8))) short  bf16x8;  // 8 bf16 = 4 VGPRs
typedef __attribute__((ext_vector_type(4))) float  f32x4;   // MFMA acc

__device__ __forceinline__ unsigned short bf16_rne(float x) {
    unsigned u = __float_as_uint(x);
    u += 0x7FFFu + ((u >> 16) & 1u);
    return (unsigned short)(u >> 16);
}
__device__ __forceinline__ float bf16_f32(unsigned short h) {
    return __uint_as_float(((unsigned)h) << 16);
}
__device__ __forceinline__ void split2(float x, unsigned short& h, unsigned short& l) {
    h = bf16_rne(x);
    l = bf16_rne(x - bf16_f32(h));
}

// ---------------------------------------------------------------------------
// Split-bf16 MFMA GEMM (NT): C[row][o] = sum_k A[row][k]*W[o][k], C ld = COUT.
// f32 = hi + lo (bf16 each); C = Ah*Bh + Al*Bh + Ah*Bl (3 MFMA passes).
// 64x64 tile, 256 threads = 4 waves (2x2), wave tile 32x32 (FM=FN=2).
// KSPLIT>1: blockIdx.z = K-chunk, accumulate via atomicAdd (C pre-zeroed).
// FUSE_STATS: per-channel sum & sumsq -> atomicAdd stats[0:C),[C:2C).
// Occupancy note: 1024 blocks = 4/CU = 16 waves/CU (vs 1 wave/SIMD in r2).
// ---------------------------------------------------------------------------
template<int K, int KSPLIT, bool FUSE_STATS>
__global__ __launch_bounds__(256)
void gemm_mfma64(const float* __restrict__ A, const float* __restrict__ W,
                 float* __restrict__ C, float* __restrict__ stats) {
    constexpr int BK = 32;          // f32 k per stage
    constexpr int LDK = 40;         // padded row length (bf16)
    constexpr int KCH = K / KSPLIT; // K-chunk per block
    __shared__ unsigned short Ah[64][LDK], Al[64][LDK];
    __shared__ unsigned short Bh[64][LDK], Bl[64][LDK];
    __shared__ float red[64][8];

    const int tid = threadIdx.x;
    const int m0 = blockIdx.y * 64;
    const int o0 = blockIdx.x * 64;
    const int kbase = blockIdx.z * KCH;
    const int lane = tid & 63, wid = tid >> 6;
    const int wy = wid >> 1, wx = wid & 1;
    const int lr = lane & 15, lg = lane >> 4;
    const int srow = tid >> 3;            // 0..31 staging row
    const int squad = (tid & 7) * 4;      // staging k offset (float4)

    f32x4 acc[2][2];
    #pragma unroll
    for (int i = 0; i < 2; ++i)
        #pragma unroll
        for (int j = 0; j < 2; ++j)
            acc[i][j] = (f32x4){0.f, 0.f, 0.f, 0.f};

    const float* Abase = A + (size_t)m0 * K + kbase + squad;
    const float* Wbase = W + (size_t)o0 * K + kbase + squad;

    for (int k0 = 0; k0 < KCH; k0 += BK) {
        __syncthreads();   // previous iteration's frag reads done
        #pragma unroll
        for (int rr = 0; rr < 2; ++rr) {
            const int r = srow + rr * 32;
            float4 va = *(const float4*)(Abase + (size_t)r * K + k0);
            float4 vb = *(const float4*)(Wbase + (size_t)r * K + k0);
            ushort4 h, l;
            split2(va.x, h.x, l.x); split2(va.y, h.y, l.y);
            split2(va.z, h.z, l.z); split2(va.w, h.w, l.w);
            *(ushort4*)&Ah[r][squad] = h;
            *(ushort4*)&Al[r][squad] = l;
            split2(vb.x, h.x, l.x); split2(vb.y, h.y, l.y);
            split2(vb.z, h.z, l.z); split2(vb.w, h.w, l.w);
            *(ushort4*)&Bh[r][squad] = h;
            *(ushort4*)&Bl[r][squad] = l;
        }
        __syncthreads();

        bf16x8 fah[2], fal[2], fbh[2], fbl[2];
        #pragma unroll
        for (int i = 0; i < 2; ++i) {
            const int row = wy * 32 + i * 16 + lr;
            fah[i] = *(const bf16x8*)&Ah[row][lg * 8];
            fal[i] = *(const bf16x8*)&Al[row][lg * 8];
        }
        #pragma unroll
        for (int j = 0; j < 2; ++j) {
            const int row = wx * 32 + j * 16 + lr;
            fbh[j] = *(const bf16x8*)&Bh[row][lg * 8];
            fbl[j] = *(const bf16x8*)&Bl[row][lg * 8];
        }
        #pragma unroll
        for (int i = 0; i < 2; ++i)
            #pragma unroll
            for (int j = 0; j < 2; ++j) {
                acc[i][j] = __builtin_amdgcn_mfma_f32_16x16x32_bf16(fah[i], fbh[j], acc[i][j], 0, 0, 0);
                acc[i][j] = __builtin_amdgcn_mfma_f32_16x16x32_bf16(fal[i], fbh[j], acc[i][j], 0, 0, 0);
                acc[i][j] = __builtin_amdgcn_mfma_f32_16x16x32_bf16(fah[i], fbl[j], acc[i][j], 0, 0, 0);
            }
    }

    // C store: D lane mapping col = lane&15, row = (lane>>4)*4 + reg
    #pragma unroll
    for (int i = 0; i < 2; ++i)
        #pragma unroll
        for (int j = 0; j < 2; ++j) {
            const int col = o0 + wx * 32 + j * 16 + lr;
            const int rbase = m0 + wy * 32 + i * 16 + lg * 4;
            #pragma unroll
            for (int r = 0; r < 4; ++r) {
                if (KSPLIT > 1)
                    atomicAdd(&C[(size_t)(rbase + r) * COUT + col], acc[i][j][r]);
                else
                    C[(size_t)(rbase + r) * COUT + col] = acc[i][j][r];
            }
        }

    if constexpr (FUSE_STATS) {
        #pragma unroll
        for (int j = 0; j < 2; ++j) {
            float s = 0.f;
            #pragma unroll
            for (int i = 0; i < 2; ++i)
                #pragma unroll
                for (int r = 0; r < 4; ++r)
                    s += acc[i][j][r];
            red[wx * 32 + j * 16 + lr][wy * 4 + lg] = s;
        }
        __syncthreads();
        if (tid < 64) {
            float s = 0.f;
            #pragma unroll
            for (int k = 0; k < 8; ++k) s += red[tid][k];
            atomicAdd(&stats[o0 + tid], s);
        }
        __syncthreads();
        #pragma unroll
        for (int j = 0; j < 2; ++j) {
            float q = 0.f;
            #pragma unroll
            for (int i = 0; i < 2; ++i)
                #pragma unroll
                for (int r = 0; r < 4; ++r)
                    q = fmaf(acc[i][j][r], acc[i][j][r], q);
            red[wx * 32 + j * 16 + lr][wy * 4 + lg] = q;
        }
        __syncthreads();
        if (tid < 64) {
            float q = 0.f;
            #pragma unroll
            for (int k = 0; k < 8; ++k) q += red[tid][k];
            atomicAdd(&stats[COUT + o0 + tid], q);
        }
    }
}

// ---------------------------------------------------------------------------
// Column sums (per-channel sum & sumsq) -> atomics into out[0:256),[256:512).
// ---------------------------------------------------------------------------
__global__ __launch_bounds__(256)
void colsum256(const float* __restrict__ X, int rowsPerBlock,
               float* __restrict__ out) {
    const int c = threadIdx.x;
    const int r0 = blockIdx.x * rowsPerBlock;
    float s = 0.f, q = 0.f;
    for (int r = 0; r < rowsPerBlock; ++r) {
        float v = X[(size_t)(r0 + r) * COUT + c];
        s += v;
        q = fmaf(v, v, q);
    }
    atomicAdd(&out[c], s);
    atomicAdd(&out[COUT + c], q);
}

// ---------------------------------------------------------------------------
// three_nn phase 1: each block = 256 queries x one 128-point chunk.
// ---------------------------------------------------------------------------
__global__ __launch_bounds__(256)
void three_nn_part(const float* __restrict__ p1, const float* __restrict__ p2,
                   float2* __restrict__ part) {
    __shared__ float4 pts[CHUNK];
    const int b = blockIdx.z;
    const int c = blockIdx.y;
    const int t = threadIdx.x;
    const int n0 = c * CHUNK;
    if (t < CHUNK) {
        const float* P1 = p1 + ((size_t)b * NPTS + n0) * 3;
        float x = P1[t * 3 + 0], y = P1[t * 3 + 1], z = P1[t * 3 + 2];
        pts[t] = make_float4(x, y, z, x * x + y * y + z * z);
    }
    __syncthreads();
    const int m = blockIdx.x * 256 + t;
    const float* q = p2 + ((size_t)b * MPTS + m) * 3;
    const float qx = q[0], qy = q[1], qz = q[2];
    const float s2 = qx * qx + qy * qy + qz * qz;
    float d0 = 1e30f, d1 = 1e30f, d2 = 1e30f;
    int   i0 = 0,     i1 = 0,     i2 = 0;
    #pragma unroll 4
    for (int n = 0; n < CHUNK; ++n) {
        float4 p = pts[n];
        float dot = p.x * qx + p.y * qy + p.z * qz;
        float d = s2 + p.w - 2.0f * dot;   // same algebraic form as reference
        if (d < d2) {                      // strict '<': earliest index wins ties
            if (d < d1) {
                d2 = d1; i2 = i1;
                if (d < d0) { d1 = d0; i1 = i0; d0 = d; i0 = n0 + n; }
                else        { d1 = d;  i1 = n0 + n; }
            } else { d2 = d; i2 = n0 + n; }
        }
    }
    float2* o = part + ((size_t)(b * MPTS + m) * NCHUNK + c) * 3;
    o[0] = make_float2(d0, __int_as_float(i0));
    o[1] = make_float2(d1, __int_as_float(i1));
    o[2] = make_float2(d2, __int_as_float(i2));
}

// ---------------------------------------------------------------------------
// three_nn phase 2: merge NCHUNK partial top-3 lists (chunk order = ascending
// index order -> strict '<' keeps reference tie-order), compute weights.
// ---------------------------------------------------------------------------
__global__ __launch_bounds__(256)
void three_nn_merge(const float2* __restrict__ part,
                    int* __restrict__ idx, float* __restrict__ wgt) {
    const int row = blockIdx.x * 256 + threadIdx.x;   // b*MPTS + m
    const float4* pp = (const float4*)(part + (size_t)row * NCHUNK * 3);
    float d0 = 1e30f, d1 = 1e30f, d2 = 1e30f;
    int   i0 = 0,     i1 = 0,     i2 = 0;
    #pragma unroll
    for (int j = 0; j < NCHUNK * 3 / 2; ++j) {        // 24 float4 = 48 pairs
        float4 v = pp[j];
        #pragma unroll
        for (int h = 0; h < 2; ++h) {
            float d = h ? v.z : v.x;
            int   i = __float_as_int(h ? v.w : v.y);
            if (d < d2) {
                if (d < d1) {
                    d2 = d1; i2 = i1;
                    if (d < d0) { d1 = d0; i1 = i0; d0 = d; i0 = i; }
                    else        { d1 = d;  i1 = i; }
                } else { d2 = d; i2 = i; }
            }
        }
    }
    const float r0 = 1.0f / (d0 + NN_EPS);
    const float r1 = 1.0f / (d1 + NN_EPS);
    const float r2 = 1.0f / (d2 + NN_EPS);
    const float rs = r0 + r1 + r2;
    const size_t o = (size_t)row * 3;
    idx[o + 0] = i0; idx[o + 1] = i1; idx[o + 2] = i2;
    wgt[o + 0] = r0 / rs; wgt[o + 1] = r1 / rs; wgt[o + 2] = r2 / rs;
}

// ---------------------------------------------------------------------------
// Final: out[row][c] = relu(BN2(h2pre)) + sum_k w_k*relu(BN1(h1pre[idx_k][c]))
// float4-vectorized: 64 lanes per row, 4 rows per block.
// stats layout: [0:256)=sum1 [256:512)=sq1 [512:768)=sum2 [768:1024)=sq2
// ---------------------------------------------------------------------------
__global__ __launch_bounds__(256)
void final_combine(const float* __restrict__ h1, const float* __restrict__ stats,
                   const float* __restrict__ g1, const float* __restrict__ b1,
                   const float* __restrict__ g2, const float* __restrict__ b2,
                   const int* __restrict__ idx, const float* __restrict__ wgt,
                   float* __restrict__ out) {
    const int t = threadIdx.x;
    const int row = blockIdx.x * 4 + (t >> 6);   // b*M + m
    const int c = (t & 63) * 4;
    const int b = row >> 13;                     // /8192

    const float4 sum1 = *(const float4*)&stats[c];
    const float4 sq1  = *(const float4*)&stats[COUT + c];
    const float4 sum2 = *(const float4*)&stats[512 + c];
    const float4 sq2  = *(const float4*)&stats[768 + c];
    const float4 gg1  = *(const float4*)&g1[c];
    const float4 bb1  = *(const float4*)&b1[c];
    const float4 gg2  = *(const float4*)&g2[c];
    const float4 bb2  = *(const float4*)&b2[c];

    const float inv1 = 1.0f / (float)ROWS1, inv2 = 1.0f / (float)ROWS2;
    float4 sc1, sh1, sc2, sh2;
    {
        float m, v;
        m = sum1.x*inv1; v = fmaf(-m,m,sq1.x*inv1); sc1.x = gg1.x/sqrtf(v+BN_EPS); sh1.x = fmaf(-m,sc1.x,bb1.x);
        m = sum1.y*inv1; v = fmaf(-m,m,sq1.y*inv1); sc1.y = gg1.y/sqrtf(v+BN_EPS); sh1.y = fmaf(-m,sc1.y,bb1.y);
        m = sum1.z*inv1; v = fmaf(-m,m,sq1.z*inv1); sc1.z = gg1.z/sqrtf(v+BN_EPS); sh1.z = fmaf(-m,sc1.z,bb1.z);
        m = sum1.w*inv1; v = fmaf(-m,m,sq1.w*inv1); sc1.w = gg1.w/sqrtf(v+BN_EPS); sh1.w = fmaf(-m,sc1.w,bb1.w);
        m = sum2.x*inv2; v = fmaf(-m,m,sq2.x*inv2); sc2.x = gg2.x/sqrtf(v+BN_EPS); sh2.x = fmaf(-m,sc2.x,bb2.x);
        m = sum2.y*inv2; v = fmaf(-m,m,sq2.y*inv2); sc2.y = gg2.y/sqrtf(v+BN_EPS); sh2.y = fmaf(-m,sc2.y,bb2.y);
        m = sum2.z*inv2; v = fmaf(-m,m,sq2.z*inv2); sc2.z = gg2.z/sqrtf(v+BN_EPS); sh2.z = fmaf(-m,sc2.z,bb2.z);
        m = sum2.w*inv2; v = fmaf(-m,m,sq2.w*inv2); sc2.w = gg2.w/sqrtf(v+BN_EPS); sh2.w = fmaf(-m,sc2.w,bb2.w);
    }

    const size_t o3 = (size_t)row * 3;
    const int i0 = idx[o3 + 0], i1 = idx[o3 + 1], i2 = idx[o3 + 2];
    const float w0 = wgt[o3 + 0], w1 = wgt[o3 + 1], w2 = wgt[o3 + 2];
    const float* hb = h1 + (size_t)b * NPTS * COUT + c;
    const float4 h0 = *(const float4*)(hb + (size_t)i0 * COUT);
    const float4 h4 = *(const float4*)(hb + (size_t)i1 * COUT);
    const float4 h8 = *(const float4*)(hb + (size_t)i2 * COUT);

    const size_t oi = (size_t)row * COUT + c;
    float4 yv = *(const float4*)&out[oi];
    float4 r;
    r.x = fmaxf(fmaf(yv.x, sc2.x, sh2.x), 0.f)
        + w0 * fmaxf(fmaf(h0.x, sc1.x, sh1.x), 0.f)
        + w1 * fmaxf(fmaf(h4.x, sc1.x, sh1.x), 0.f)
        + w2 * fmaxf(fmaf(h8.x, sc1.x, sh1.x), 0.f);
    r.y = fmaxf(fmaf(yv.y, sc2.y, sh2.y), 0.f)
        + w0 * fmaxf(fmaf(h0.y, sc1.y, sh1.y), 0.f)
        + w1 * fmaxf(fmaf(h4.y, sc1.y, sh1.y), 0.f)
        + w2 * fmaxf(fmaf(h8.y, sc1.y, sh1.y), 0.f);
    r.z = fmaxf(fmaf(yv.z, sc2.z, sh2.z), 0.f)
        + w0 * fmaxf(fmaf(h0.z, sc1.z, sh1.z), 0.f)
        + w1 * fmaxf(fmaf(h4.z, sc1.z, sh1.z), 0.f)
        + w2 * fmaxf(fmaf(h8.z, sc1.z, sh1.z), 0.f);
    r.w = fmaxf(fmaf(yv.w, sc2.w, sh2.w), 0.f)
        + w0 * fmaxf(fmaf(h0.w, sc1.w, sh1.w), 0.f)
        + w1 * fmaxf(fmaf(h4.w, sc1.w, sh1.w), 0.f)
        + w2 * fmaxf(fmaf(h8.w, sc1.w, sh1.w), 0.f);
    *(float4*)&out[oi] = r;
}

// ---------------------------------------------------------------------------
extern "C" void kernel_launch(void* const* d_in, const int* in_sizes, int n_in,
                              void* d_out, int out_size, void* d_ws, size_t ws_size,
                              hipStream_t stream) {
    const float* x1       = (const float*)d_in[0];  // (B,N,Cin1)
    const float* p1       = (const float*)d_in[1];  // (B,N,3)
    const float* x2       = (const float*)d_in[2];  // (B,M,Cin2)
    const float* p2       = (const float*)d_in[3];  // (B,M,3)
    const float* W_up     = (const float*)d_in[4];  // (COUT,CIN1)
    const float* gamma_up = (const float*)d_in[5];
    const float* beta_up  = (const float*)d_in[6];
    const float* W_lat    = (const float*)d_in[7];  // (COUT,CIN2)
    const float* gamma_lat= (const float*)d_in[8];
    const float* beta_lat = (const float*)d_in[9];
    float* out = (float*)d_out;

    // workspace layout (~11 MB)
    float*  h1    = (float*)d_ws;                        // ROWS1*COUT (pre-BN)
    float*  stats = h1 + (size_t)ROWS1 * COUT;           // 1024 floats
    int*    idx   = (int*)(stats + 1024);                // ROWS2*3
    float*  wgt   = (float*)(idx + (size_t)ROWS2 * 3);   // ROWS2*3
    float2* part  = (float2*)(wgt + (size_t)ROWS2 * 3);  // ROWS2*NCHUNK*3 float2

    hipMemsetAsync(stats, 0, 1024 * sizeof(float), stream);
    hipMemsetAsync(h1, 0, (size_t)ROWS1 * COUT * sizeof(float), stream);  // split-K acc

    // up_mlp GEMM (split-bf16 MFMA, split-K=4): 1024 blocks
    gemm_mfma64<CIN1, 4, false><<<dim3(COUT / 64, ROWS1 / 64, 4), 256, 0, stream>>>(
        x1, W_up, h1, nullptr);
    // BN1 stats from h1
    colsum256<<<256, 256, 0, stream>>>(h1, ROWS1 / 256, stats);

    // lateral GEMM into d_out's y region + fused BN2 stats: 1024 blocks
    gemm_mfma64<CIN2, 1, true><<<dim3(COUT / 64, ROWS2 / 64, 1), 256, 0, stream>>>(
        x2, W_lat, out, stats + 512);

    // 3-NN: split-N partials then merge
    three_nn_part<<<dim3(MPTS / 256, NCHUNK, BATCH), 256, 0, stream>>>(p1, p2, part);
    three_nn_merge<<<ROWS2 / 256, 256, 0, stream>>>(part, idx, wgt);

    // gather-interp (+BN1+ReLU) + BN2 + ReLU + add, in place on d_out
    final_combine<<<ROWS2 / 4, 256, 0, stream>>>(h1, stats, gamma_up, beta_up,
                                                 gamma_lat, beta_lat, idx, wgt, out);

    // p2 passthrough -> second output
    hipMemcpyAsync(out + (size_t)ROWS2 * COUT, p2,
                   (size_t)ROWS2 * 3 * sizeof(float),
                   hipMemcpyDeviceToDevice, stream);
}